// Round 13
// baseline (39.248 us; speedup 1.0000x reference)
//
#include <hip/hip_runtime.h>
#include <stdint.h>

// Floyd-Steinberg halftoning, fused, 4-lanes-per-tile, one forced load batch.
//
// Synthesis of the best proven elements from R2-R12 (which plateau 37.7-39.4us
// across five structures):
//  - 4 lanes/tile (lane q owns cols {2q,2q+1}): halves FS VALU redundancy vs
//    the 8-lane variants (x4 instead of x8) while keeping float2 granularity.
//  - ONE batch of 12 volatile inline-asm buffer_load_dwordx2 (24 data VGPRs):
//    single HBM latency exposure; the allocator cannot re-chunk it (R8's only
//    flaw was 3 serialized batches; R10 proved source batches get shredded).
//  - s_waitcnt vmcnt(0) + sched_barrier(0) before consumption (rule #18).
//  - Grid 524288 threads = 2048 blocks = 8 blocks/CU; __launch_bounds__(256,6)
//    (~85-reg cap, live set ~55 -> no spill; R6/R9 spill trap avoided).
//
// FS on the TRANSPOSED tile (reference swapaxes), redundant across the quad;
// FS row i (orig col i) owned by quad-lane i>>1, element j*2+(i&1); broadcast
// via __shfl with compile-time p index. Exact reference math, contract(off):
// ((0.114*s0)+(0.587*s1))+(0.299*s2).

#define IMG_H 1024
#define IMG_W 1024
#define NCH   3

typedef uint32_t u32x4 __attribute__((ext_vector_type(4)));
typedef float    v2f  __attribute__((ext_vector_type(2)));

__device__ __forceinline__ v2f bload2(u32x4 rsrc, uint32_t voff_bytes) {
    v2f r;
    asm volatile("buffer_load_dwordx2 %0, %1, %2, 0 offen"
                 : "=v"(r) : "v"(voff_bytes), "s"(rsrc));
    return r;
}

__global__ __launch_bounds__(256, 6)
void fs_halftone_kernel(const float* __restrict__ in, float* __restrict__ out,
                        int n_imgs) {
#pragma clang fp contract(off)
    const int tiles_w = IMG_W / 8;                 // 128
    const int tiles_per_img = tiles_w * (IMG_H / 8);

    int gtid = blockIdx.x * blockDim.x + threadIdx.x;
    int tile = gtid >> 2;
    int q    = gtid & 3;                           // owns cols {2q, 2q+1}
    int lane = threadIdx.x & 63;
    int b  = tile / tiles_per_img;
    if (b >= n_imgs) return;
    int t  = tile % tiles_per_img;
    int th = t / tiles_w;
    int tw = t % tiles_w;

    const size_t imgstride = (size_t)IMG_H * IMG_W;
    const size_t slab_off  = (size_t)b * NCH * imgstride
                           + (size_t)(th * 8) * IMG_W + (size_t)(tw * 8) + (size_t)(q * 2);
    float* obase = out + slab_off;

    // ---- SRSRC over input; 12 dwordx2 loads forced in flight, ONE wait ----
    u32x4 rsrc;
    {
        uint64_t a = (uint64_t)(uintptr_t)in;
        rsrc.x = (uint32_t)a;
        rsrc.y = (uint32_t)(a >> 32);
        rsrc.z = 0xFFFFFFFFu;                      // bounds check disabled
        rsrc.w = 0x00020000u;                      // raw dword access
    }
    const uint32_t v0 = (uint32_t)(slab_off * sizeof(float));

    v2f l0[8], l1[8], l2[8];
#pragma unroll
    for (int r = 0; r < 8; ++r) l0[r] = bload2(rsrc, v0 + (uint32_t)(0 * 4194304 + r * 4096));
#pragma unroll
    for (int r = 0; r < 8; ++r) l1[r] = bload2(rsrc, v0 + (uint32_t)(1 * 4194304 + r * 4096));
#pragma unroll
    for (int r = 0; r < 8; ++r) l2[r] = bload2(rsrc, v0 + (uint32_t)(2 * 4194304 + r * 4096));

    asm volatile("s_waitcnt vmcnt(0)" ::: "memory");
    __builtin_amdgcn_sched_barrier(0);             // rule #18

    // ---- gray (exact reference tree) + per-channel zero-masks ----
    float p[16];                                   // own gray, idx r*2+k
    unsigned int zm0 = 0u, zm1 = 0u, zm2 = 0u;     // bits r*2+k
#pragma unroll
    for (int r = 0; r < 8; ++r)
#pragma unroll
        for (int k = 0; k < 2; ++k) {
            int idx = r * 2 + k;
            float s0 = l0[r][k] * 255.0f;
            float s1 = l1[r][k] * 255.0f;
            float s2 = l2[r][k] * 255.0f;
            if (s0 == 0.0f) zm0 |= 1u << idx;
            if (s1 == 0.0f) zm1 |= 1u << idx;
            if (s2 == 0.0f) zm2 |= 1u << idx;
            p[idx] = ((0.114f * s0) + (0.587f * s1)) + (0.299f * s2);
        }

    // ---- FS on the TRANSPOSED tile (redundant across the quad) ----
    float nrow[8];
#pragma unroll
    for (int j = 0; j < 8; ++j) nrow[j] = 0.0f;

    unsigned long long hbits = 0ull;               // bit (j*8+i)

#pragma unroll
    for (int i = 0; i < 8; ++i) {
        const int oq = i >> 1, ip = i & 1;         // compile-time
        float cv[8];
#pragma unroll
        for (int j = 0; j < 8; ++j)
            cv[j] = __shfl(p[j * 2 + ip], (lane & ~3) | oq);

        float errs[8];
        float er = 0.0f;
#pragma unroll
        for (int j = 0; j < 8; ++j) {
            float px  = cv[j] + nrow[j];
            float old = px + er;
            bool  on  = old > 127.0f;
            float nw  = on ? 255.0f : 0.0f;
            float e   = old - nw;
            er = e * 0.4375f;                      // 7/16
            errs[j] = e;
            if (on) hbits |= 1ull << (j * 8 + i);
        }
#pragma unroll
        for (int j = 0; j < 8; ++j) {
            float en = (j < 7) ? errs[j + 1] : 0.0f;
            float ep = (j > 0) ? errs[j - 1] : 0.0f;
            nrow[j] = ((0.3125f * errs[j]) + (0.1875f * en)) + (0.0625f * ep);
        }
    }

    // ---- stores: own 2 columns, 3 planes (wave instr = 512B contiguous) ----
    const int c0 = q * 2;
#pragma unroll
    for (int ch = 0; ch < 3; ++ch) {
        unsigned int zm = (ch == 0) ? zm0 : ((ch == 1) ? zm1 : zm2);
#pragma unroll
        for (int r = 0; r < 8; ++r) {
            v2f v;
#pragma unroll
            for (int k = 0; k < 2; ++k) {
                bool on = (hbits >> (r * 8 + c0 + k)) & 1ull;
                bool z  = (zm    >> (r * 2 + k)) & 1u;
                v[k] = (on && !z) ? 1.0f : 0.0f;
            }
            *(v2f*)(obase + ch * imgstride + (size_t)r * IMG_W) = v;
        }
    }
}

extern "C" void kernel_launch(void* const* d_in, const int* in_sizes, int n_in,
                              void* d_out, int out_size, void* d_ws, size_t ws_size,
                              hipStream_t stream) {
    const float* in  = (const float*)d_in[0];
    float*       out = (float*)d_out;

    int n_imgs = in_sizes[0] / (NCH * IMG_H * IMG_W);  // 8
    int total_threads = 4 * n_imgs * (IMG_H / 8) * (IMG_W / 8);  // 4 per tile
    int block = 256;
    int grid = (total_threads + block - 1) / block;
    fs_halftone_kernel<<<grid, block, 0, stream>>>(in, out, n_imgs);
}